// Round 5
// baseline (1003.207 us; speedup 1.0000x reference)
//
#include <hip/hip_runtime.h>
#include <math.h>

#define NIMG 8
#define NCLS 80
#define HW 40000
#define M (NCLS*HW)          // 3,200,000 per image
#define NBINS 2048
#define BIN_SHIFT 20         // top 12 bits of positive float
#define CAND_MAX 4096
#define SPILL_CAP 65536
#define TOPK 1000
#define OUTK 100
#define PRE_T 0.05f
#define NMS_T 0.6f
#define FLOOR_S 0.25f        // fast-path floor: verified per-call via c025>=TOPK
#define FLOOR_SAFE 0.2494f   // spill threshold with margin for logit rounding

// device-global scratch; counters re-zeroed every call, rest guarded by counts
__device__ unsigned int       g_scnt[NIMG];
__device__ int                g_flag[NIMG];
__device__ float              g_xthr[NIMG * HW];       // 1.25 MB, L2-resident
__device__ unsigned int       g_spill[NIMG][SPILL_CAP];
__device__ unsigned long long g_key[NIMG][SPILL_CAP];
__device__ unsigned long long g_top[NIMG][1024];

__device__ __forceinline__ float sigmoid_exact(float x){
    return 1.0f / (1.0f + expf(-x));   // bit-matches ref (R1-R4: absmax 0)
}

// k0: zero counters; xthr[hw] = logit(FLOOR_SAFE / sigmoid(ct)), +inf if >=1.
// Spill rule x >= xthr is a strict superset of {exact score >= FLOOR_S}:
// 0.2494 vs 0.25 gives 2.4e-3 rel margin; logit amplification capped by the
// 0.98 clamp (1/(1-a) <= 50) -> margin ~0.12 in x-units vs ~1e-5 error.
__global__ void k0_init(const float* __restrict__ cent){
    int t = blockIdx.x * blockDim.x + threadIdx.x;
    if (t < NIMG) g_scnt[t] = 0u;
    if (t < NIMG * HW){
        float pct = sigmoid_exact(cent[t]);
        float a = FLOOR_SAFE / pct;
        float xt;
        if (a >= 1.0f) xt = 3.0e38f;           // score can never reach floor
        else {
            float am = fminf(a, 0.98f);
            xt = logf(am / (1.0f - am));
        }
        g_xthr[t] = xt;
    }
}

// k1: the ONLY full stream over cls. One float4 per thread, no loop, no
// sigmoid, no histogram: compare raw logits against the precomputed per-pixel
// threshold; rare spills (~0.4%) wave-aggregated into g_spill.
__global__ void __launch_bounds__(256) k1_spill(const float* __restrict__ cls){
    const int n   = blockIdx.y;
    const int tid = threadIdx.x;
    const int e0  = (blockIdx.x * 256 + tid) * 4;    // grid covers M exactly
    const int c   = e0 / HW;                          // magic-mul
    const int hw  = e0 - c * HW;                      // hw%4==0, same class x4
    float4 x  = *(const float4*)(cls + (size_t)n * M + e0);
    float4 th = *(const float4*)(g_xthr + n * HW + hw);
    bool s0 = x.x >= th.x, s1 = x.y >= th.y, s2 = x.z >= th.z, s3 = x.w >= th.w;
    unsigned long long m0 = __ballot(s0), m1 = __ballot(s1);
    unsigned long long m2 = __ballot(s2), m3 = __ballot(s3);
    unsigned int c0 = __popcll(m0), c1 = __popcll(m1);
    unsigned int c2 = __popcll(m2), c3 = __popcll(m3);
    unsigned int total = c0 + c1 + c2 + c3;
    int lane = tid & 63;
    unsigned int base = 0;
    if (lane == 0 && total) base = atomicAdd(&g_scnt[n], total);
    base = (unsigned int)__builtin_amdgcn_readfirstlane((int)base);
    unsigned long long lm = (1ull << lane) - 1ull;
    if (s0){ unsigned int p = base + __popcll(m0 & lm);
             if (p < SPILL_CAP) g_spill[n][p] = (unsigned int)((hw+0)*NCLS + c); }
    if (s1){ unsigned int p = base + c0 + __popcll(m1 & lm);
             if (p < SPILL_CAP) g_spill[n][p] = (unsigned int)((hw+1)*NCLS + c); }
    if (s2){ unsigned int p = base + c0 + c1 + __popcll(m2 & lm);
             if (p < SPILL_CAP) g_spill[n][p] = (unsigned int)((hw+2)*NCLS + c); }
    if (s3){ unsigned int p = base + c0 + c1 + c2 + __popcll(m3 & lm);
             if (p < SPILL_CAP) g_spill[n][p] = (unsigned int)((hw+3)*NCLS + c); }
}

// k4: per image — exact re-score spilled (~13K), exact-bits histogram, cut,
// collect, exact rank-select top-1000. Sets fallback flag if floor unproven.
__global__ void __launch_bounds__(1024) k4_select(const float* __restrict__ cls,
                                                  const float* __restrict__ cent){
    const int n = blockIdx.x;
    const int tid = threadIdx.x;
    __shared__ unsigned int hist[NBINS];
    __shared__ unsigned int csum[256];
    __shared__ unsigned long long keys[CAND_MAX];
    __shared__ unsigned int lcnt, c025, s_cut, s_flag;
    for (int i = tid; i < NBINS; i += 1024) hist[i] = 0u;
    if (tid == 0){ lcnt = 0u; c025 = 0u; }
    g_top[n][tid] = 0ull;
    __syncthreads();
    unsigned int scnt_raw = g_scnt[n];
    unsigned int S = scnt_raw < SPILL_CAP ? scnt_raw : SPILL_CAP;
    const float* cls_n  = cls  + (size_t)n * M;
    const float* cent_n = cent + (size_t)n * HW;
    for (unsigned int i = tid; i < S; i += 1024){
        unsigned int idx = g_spill[n][i];
        unsigned int hw = idx / NCLS;
        unsigned int c  = idx - hw * NCLS;
        float x  = cls_n[(size_t)c * HW + hw];
        float ct = cent_n[hw];
        float p = sigmoid_exact(x);
        unsigned long long key = 0ull;
        if (p > PRE_T){
            float s = p * sigmoid_exact(ct);
            unsigned int bits = __float_as_uint(s);
            atomicAdd(&hist[bits >> BIN_SHIFT], 1u);
            if (s >= FLOOR_S) atomicAdd(&c025, 1u);
            key = ((unsigned long long)bits << 32)
                | (unsigned long long)(0xFFFFFFFFu - idx);
        }
        g_key[n][i] = key;
    }
    __syncthreads();
    if (tid < 256){
        unsigned int s = 0;
        int base = tid * 8;
        #pragma unroll
        for (int i = 0; i < 8; ++i) s += hist[base + i];
        csum[tid] = s;
    }
    __syncthreads();
    if (tid == 0){
        unsigned int acc = 0; int cut = 0; int c = 255;
        for (; c >= 0; --c){ if (acc + csum[c] >= TOPK) break; acc += csum[c]; }
        if (c >= 0){
            int b = c*8 + 7;
            for (;; --b){ acc += hist[b]; if (acc >= TOPK || b == c*8) break; }
            cut = b;
        }
        // flag: spill overflow, floor unproven, or cut-bin tie-storm
        unsigned int fl = (scnt_raw > SPILL_CAP) || (c025 < TOPK) ||
                          (acc > CAND_MAX) ? 1u : 0u;
        s_cut = (unsigned int)cut; s_flag = fl; g_flag[n] = (int)fl;
    }
    __syncthreads();
    if (s_flag) return;      // k4b rebuilds g_top from scratch
    unsigned int cutb = s_cut;
    for (unsigned int i = tid; i < S; i += 1024){
        unsigned long long k = g_key[n][i];
        if (k && (unsigned int)(k >> (32 + BIN_SHIFT)) >= cutb){
            unsigned int pos = atomicAdd(&lcnt, 1u);
            if (pos < CAND_MAX) keys[pos] = k;
        }
    }
    __syncthreads();
    int C = (int)(lcnt < CAND_MAX ? lcnt : CAND_MAX);
    for (int i = tid; i < C; i += 1024){
        unsigned long long k = keys[i];
        int rank = 0;
        for (int j = 0; j < C; ++j) rank += (keys[j] > k) ? 1 : 0;
        if (rank < TOPK) g_top[n][rank] = k;
    }
}

// k4b: guaranteed-correct full exact rescan; normally early-exits (~flag==0).
__global__ void __launch_bounds__(1024) k4b_fallback(const float* __restrict__ cls,
                                                     const float* __restrict__ cent){
    const int n = blockIdx.x;
    if (!g_flag[n]) return;
    const int tid = threadIdx.x;
    __shared__ unsigned int hist[NBINS];
    __shared__ unsigned int csum[256];
    __shared__ unsigned long long keys[CAND_MAX];
    __shared__ unsigned int lcnt, s_cut;
    for (int i = tid; i < NBINS; i += 1024) hist[i] = 0u;
    if (tid == 0) lcnt = 0u;
    g_top[n][tid] = 0ull;
    __syncthreads();
    const float* cls_n  = cls  + (size_t)n * M;
    const float* cent_n = cent + (size_t)n * HW;
    for (int e = tid; e < M; e += 1024){
        float p = sigmoid_exact(cls_n[e]);
        if (p > PRE_T){
            int c = e / HW; int hw = e - c * HW;
            float s = p * sigmoid_exact(cent_n[hw]);
            atomicAdd(&hist[__float_as_uint(s) >> BIN_SHIFT], 1u);
        }
    }
    __syncthreads();
    if (tid < 256){
        unsigned int s = 0;
        int base = tid * 8;
        #pragma unroll
        for (int i = 0; i < 8; ++i) s += hist[base + i];
        csum[tid] = s;
    }
    __syncthreads();
    if (tid == 0){
        unsigned int acc = 0; int cut = 0; int c = 255;
        for (; c >= 0; --c){ if (acc + csum[c] >= TOPK) break; acc += csum[c]; }
        if (c >= 0){
            int b = c*8 + 7;
            for (;; --b){ acc += hist[b]; if (acc >= TOPK || b == c*8) break; }
            cut = b;
        }
        while (acc > CAND_MAX && cut < NBINS){ acc -= hist[cut]; cut++; }
        s_cut = (unsigned int)cut;
    }
    __syncthreads();
    unsigned int cutb = s_cut;
    for (int e = tid; e < M; e += 1024){
        float p = sigmoid_exact(cls_n[e]);
        if (p > PRE_T){
            int c = e / HW; int hw = e - c * HW;
            float s = p * sigmoid_exact(cent_n[hw]);
            unsigned int bits = __float_as_uint(s);
            if ((bits >> BIN_SHIFT) >= cutb){
                unsigned int pos = atomicAdd(&lcnt, 1u);
                if (pos < CAND_MAX){
                    unsigned int idx = (unsigned int)(hw * NCLS + c);
                    keys[pos] = ((unsigned long long)bits << 32)
                              | (unsigned long long)(0xFFFFFFFFu - idx);
                }
            }
        }
    }
    __syncthreads();
    int C = (int)(lcnt < CAND_MAX ? lcnt : CAND_MAX);
    for (int i = tid; i < C; i += 1024){
        unsigned long long k = keys[i];
        int rank = 0;
        for (int j = 0; j < C; ++j) rank += (keys[j] > k) ? 1 : 0;
        if (rank < TOPK) g_top[n][rank] = k;
    }
}

// k5: decode boxes, greedy NMS with early stop at 100 keeps, write output
__global__ void __launch_bounds__(1024) k5_nms(const float* __restrict__ loc,
                                               const float* __restrict__ reg,
                                               const int*   __restrict__ imsz,
                                               float* __restrict__ out){
    int n = blockIdx.x;
    int t = threadIdx.x;
    __shared__ float ox1[TOPK], oy1[TOPK], ox2[TOPK], oy2[TOPK], oar[TOPK];
    __shared__ float bx[TOPK][4];
    __shared__ float sc[TOPK];
    __shared__ int   lab[TOPK];
    __shared__ unsigned char validf[TOPK];
    __shared__ unsigned char supp[TOPK];
    __shared__ int keeplist[OUTK];

    if (t < TOPK){
        unsigned long long k = g_top[n][t];
        unsigned int bits = (unsigned int)(k >> 32);
        float s = __uint_as_float(bits);
        supp[t] = 0;
        if (s > 0.0f){
            unsigned int idx = 0xFFFFFFFFu - (unsigned int)(k & 0xFFFFFFFFull);
            int hw = (int)(idx / NCLS);
            int c  = (int)(idx % NCLS);
            int l  = c + 1;
            float x  = loc[2*hw], y = loc[2*hw + 1];
            float r0 = reg[((size_t)n*4 + 0)*HW + hw];
            float r1 = reg[((size_t)n*4 + 1)*HW + hw];
            float r2 = reg[((size_t)n*4 + 2)*HW + hw];
            float r3 = reg[((size_t)n*4 + 3)*HW + hw];
            float ihh = (float)imsz[2*n + 0];
            float iww = (float)imsz[2*n + 1];
            float x1 = fminf(fmaxf(x - r0, 0.0f), iww - 1.0f);
            float y1 = fminf(fmaxf(y - r1, 0.0f), ihh - 1.0f);
            float x2 = fminf(fmaxf(x + r2, 0.0f), iww - 1.0f);
            float y2 = fminf(fmaxf(y + r3, 0.0f), ihh - 1.0f);
            bx[t][0] = x1; bx[t][1] = y1; bx[t][2] = x2; bx[t][3] = y2;
            float off = (float)l * 100000.0f;   // fp32, as reference (quantizes!)
            float a1 = x1 + off, b1 = y1 + off, a2 = x2 + off, b2 = y2 + off;
            ox1[t] = a1; oy1[t] = b1; ox2[t] = a2; oy2[t] = b2;
            oar[t] = (a2 - a1 + 1.0f) * (b2 - b1 + 1.0f);
            sc[t] = s; lab[t] = l; validf[t] = 1;
        } else {
            validf[t] = 0; sc[t] = 0.0f; lab[t] = 0;
            bx[t][0] = bx[t][1] = bx[t][2] = bx[t][3] = 0.0f;
            ox1[t] = oy1[t] = 0.0f; ox2[t] = oy2[t] = -1.0f; oar[t] = 1.0f;
        }
    }
    __syncthreads();

    int cnt = 0;
    for (int i = 0; i < TOPK; ++i){
        bool keep_i = validf[i] && !supp[i];   // uniform LDS broadcast
        if (keep_i){
            if (t == 0) keeplist[cnt] = i;
            if (t < TOPK && t != i){
                float ix1 = fmaxf(ox1[i], ox1[t]);
                float iy1 = fmaxf(oy1[i], oy1[t]);
                float ix2 = fminf(ox2[i], ox2[t]);
                float iy2 = fminf(oy2[i], oy2[t]);
                float iw_ = fmaxf(ix2 - ix1 + 1.0f, 0.0f);
                float ih_ = fmaxf(iy2 - iy1 + 1.0f, 0.0f);
                float inter = iw_ * ih_;
                float iou = inter / (oar[i] + oar[t] - inter);
                if (iou > NMS_T) supp[t] = 1;
            }
            cnt++;
            __syncthreads();
            if (cnt == OUTK) break;    // keeps beyond 100 can't reach output
        }
    }
    __syncthreads();

    if (t < OUTK){
        float r0=0.f,r1=0.f,r2=0.f,r3=0.f,r4=0.f,r5=0.f;
        if (t < cnt){
            int i = keeplist[t];
            r0 = bx[i][0]; r1 = bx[i][1]; r2 = bx[i][2]; r3 = bx[i][3];
            r4 = sqrtf(sc[i]); r5 = (float)lab[i];
        }
        float* o = out + ((size_t)n*OUTK + t)*6;
        o[0]=r0; o[1]=r1; o[2]=r2; o[3]=r3; o[4]=r4; o[5]=r5;
    }
}

extern "C" void kernel_launch(void* const* d_in, const int* in_sizes, int n_in,
                              void* d_out, int out_size, void* d_ws, size_t ws_size,
                              hipStream_t stream){
    const float* loc  = (const float*)d_in[0];
    const float* cls  = (const float*)d_in[1];
    const float* reg  = (const float*)d_in[2];
    const float* cent = (const float*)d_in[3];
    const int*   imsz = (const int*)d_in[4];
    float* out = (float*)d_out;

    hipLaunchKernelGGL(k0_init,      dim3(625, 1, 1),     dim3(512),  0, stream, cent);
    hipLaunchKernelGGL(k1_spill,     dim3(M/1024, NIMG),  dim3(256),  0, stream, cls);
    hipLaunchKernelGGL(k4_select,    dim3(NIMG),          dim3(1024), 0, stream, cls, cent);
    hipLaunchKernelGGL(k4b_fallback, dim3(NIMG),          dim3(1024), 0, stream, cls, cent);
    hipLaunchKernelGGL(k5_nms,       dim3(NIMG),          dim3(1024), 0, stream,
                       loc, reg, imsz, out);
}

// Round 6
// 336.605 us; speedup vs baseline: 2.9804x; 2.9804x over previous
//
#include <hip/hip_runtime.h>
#include <math.h>

#define NIMG 8
#define NCLS 80
#define HW 40000
#define M (NCLS*HW)          // 3,200,000 per image
#define NBINS 2048
#define BIN_SHIFT 20         // top 12 bits of positive float
#define CAND_MAX 4096
#define SPILL_CAP 65536
#define BCAP 1024            // per-block spill buffer (expected ~6 spills/block)
#define TOPK 1000
#define OUTK 100
#define PRE_T 0.05f
#define NMS_T 0.6f
#define FLOOR_S 0.25f        // fast-path floor: verified per-call via c025>=TOPK
#define FLOOR_SAFE 0.2494f   // spill threshold with margin for logit rounding

// device-global scratch; counters re-zeroed every call, rest guarded by counts
__device__ unsigned int       g_scnt[NIMG][32];    // padded: 128B per image
__device__ unsigned int       g_ovf[NIMG];
__device__ int                g_flag[NIMG];
__device__ float              g_xthr[NIMG * HW];   // 1.25 MB, L2-resident
__device__ unsigned int       g_spill[NIMG][SPILL_CAP];
__device__ unsigned long long g_key[NIMG][SPILL_CAP];
__device__ unsigned long long g_top[NIMG][1024];

__device__ __forceinline__ float sigmoid_exact(float x){
    return 1.0f / (1.0f + expf(-x));   // bit-matches ref (R1-R5: absmax 0)
}

// k0: zero counters; xthr[hw] = logit(FLOOR_SAFE / sigmoid(ct)), +inf if >=1.
// Spill rule x >= xthr is a strict superset of {exact score >= FLOOR_S}:
// 0.2494 vs 0.25 = 2.4e-3 rel margin; logit slope capped by the 0.98 clamp
// (|dx/da| <= 1/(a(1-a)) ~ 51) -> margin ~0.12 in x-units vs ~1e-5 rounding.
__global__ void k0_init(const float* __restrict__ cent){
    int t = blockIdx.x * blockDim.x + threadIdx.x;
    if (t < NIMG * 32) ((unsigned int*)g_scnt)[t] = 0u;
    if (t < NIMG) g_ovf[t] = 0u;
    if (t < NIMG * HW){
        float pct = sigmoid_exact(cent[t]);
        float a = FLOOR_SAFE / pct;
        float xt;
        if (a >= 1.0f) xt = 3.0e38f;           // score can never reach floor
        else {
            float am = fminf(a, 0.98f);
            xt = logf(am / (1.0f - am));
        }
        g_xthr[t] = xt;
    }
}

// k1: the ONLY full stream over cls. One float4 per thread, no loop, no
// sigmoid: raw-logit compare vs precomputed per-pixel threshold. Spills are
// compacted in LDS; ONE global atomic per block to a padded per-image counter
// (R5 post-mortem: per-wave atomics to one shared cache line cost ~700us).
__global__ void __launch_bounds__(1024) k1_spill(const float* __restrict__ cls){
    const int n   = blockIdx.y;
    const int tid = threadIdx.x;
    const int e0  = blockIdx.x * 4096 + tid * 4;
    __shared__ unsigned int sidx[BCAP];
    __shared__ unsigned int lcnt, lbase;
    if (tid == 0) lcnt = 0u;
    __syncthreads();
    if (e0 < M){                       // M%4==0; full float4 valid when e0<M
        const int c  = e0 / HW;        // 4-aligned group never crosses class
        const int hw = e0 - c * HW;    // boundary (HW%4==0)
        float4 x  = *(const float4*)(cls + (size_t)n * M + e0);
        float4 th = *(const float4*)(g_xthr + n * HW + hw);
        unsigned int ib = (unsigned int)(hw * NCLS + c);
        if (x.x >= th.x){ unsigned int p = atomicAdd(&lcnt, 1u); if (p < BCAP) sidx[p] = ib; }
        if (x.y >= th.y){ unsigned int p = atomicAdd(&lcnt, 1u); if (p < BCAP) sidx[p] = ib + NCLS; }
        if (x.z >= th.z){ unsigned int p = atomicAdd(&lcnt, 1u); if (p < BCAP) sidx[p] = ib + 2*NCLS; }
        if (x.w >= th.w){ unsigned int p = atomicAdd(&lcnt, 1u); if (p < BCAP) sidx[p] = ib + 3*NCLS; }
    }
    __syncthreads();
    unsigned int raw = lcnt;
    unsigned int cnt = raw < BCAP ? raw : BCAP;
    if (tid == 0){
        lbase = cnt ? atomicAdd(&g_scnt[n][0], cnt) : 0u;
        if (raw > BCAP) g_ovf[n] = 1u;     // forces exact full-rescan fallback
    }
    __syncthreads();
    unsigned int base = lbase;
    for (unsigned int i = tid; i < cnt; i += 1024){
        unsigned int pos = base + i;
        if (pos < SPILL_CAP) g_spill[n][pos] = sidx[i];
    }
}

// k4: per image — exact re-score spilled (~5K), exact-bits histogram, cut,
// collect, exact rank-select top-1000. Sets fallback flag if floor unproven.
__global__ void __launch_bounds__(1024) k4_select(const float* __restrict__ cls,
                                                  const float* __restrict__ cent){
    const int n = blockIdx.x;
    const int tid = threadIdx.x;
    __shared__ unsigned int hist[NBINS];
    __shared__ unsigned int csum[256];
    __shared__ unsigned long long keys[CAND_MAX];
    __shared__ unsigned int lcnt, c025, s_cut, s_flag;
    for (int i = tid; i < NBINS; i += 1024) hist[i] = 0u;
    if (tid == 0){ lcnt = 0u; c025 = 0u; }
    g_top[n][tid] = 0ull;
    __syncthreads();
    unsigned int scnt_raw = g_scnt[n][0];
    unsigned int S = scnt_raw < SPILL_CAP ? scnt_raw : SPILL_CAP;
    const float* cls_n  = cls  + (size_t)n * M;
    const float* cent_n = cent + (size_t)n * HW;
    for (unsigned int i = tid; i < S; i += 1024){
        unsigned int idx = g_spill[n][i];
        unsigned int hw = idx / NCLS;
        unsigned int c  = idx - hw * NCLS;
        float x  = cls_n[(size_t)c * HW + hw];
        float ct = cent_n[hw];
        float p = sigmoid_exact(x);
        unsigned long long key = 0ull;
        if (p > PRE_T){
            float s = p * sigmoid_exact(ct);
            unsigned int bits = __float_as_uint(s);
            atomicAdd(&hist[bits >> BIN_SHIFT], 1u);
            if (s >= FLOOR_S) atomicAdd(&c025, 1u);
            key = ((unsigned long long)bits << 32)
                | (unsigned long long)(0xFFFFFFFFu - idx);
        }
        g_key[n][i] = key;
    }
    __syncthreads();
    if (tid < 256){
        unsigned int s = 0;
        int base = tid * 8;
        #pragma unroll
        for (int i = 0; i < 8; ++i) s += hist[base + i];
        csum[tid] = s;
    }
    __syncthreads();
    if (tid == 0){
        unsigned int acc = 0; int cut = 0; int c = 255;
        for (; c >= 0; --c){ if (acc + csum[c] >= TOPK) break; acc += csum[c]; }
        if (c >= 0){
            int b = c*8 + 7;
            for (;; --b){ acc += hist[b]; if (acc >= TOPK || b == c*8) break; }
            cut = b;
        }
        // flag: spill/LDS overflow, floor unproven, or cut-bin tie-storm
        unsigned int fl = (scnt_raw > SPILL_CAP) || g_ovf[n] ||
                          (c025 < TOPK) || (acc > CAND_MAX) ? 1u : 0u;
        s_cut = (unsigned int)cut; s_flag = fl; g_flag[n] = (int)fl;
    }
    __syncthreads();
    if (s_flag) return;      // k4b rebuilds g_top from scratch
    unsigned int cutb = s_cut;
    for (unsigned int i = tid; i < S; i += 1024){
        unsigned long long k = g_key[n][i];
        if (k && (unsigned int)(k >> (32 + BIN_SHIFT)) >= cutb){
            unsigned int pos = atomicAdd(&lcnt, 1u);
            if (pos < CAND_MAX) keys[pos] = k;
        }
    }
    __syncthreads();
    int C = (int)(lcnt < CAND_MAX ? lcnt : CAND_MAX);
    for (int i = tid; i < C; i += 1024){
        unsigned long long k = keys[i];
        int rank = 0;
        for (int j = 0; j < C; ++j) rank += (keys[j] > k) ? 1 : 0;
        if (rank < TOPK) g_top[n][rank] = k;
    }
}

// k4b: guaranteed-correct full exact rescan; normally early-exits (flag==0).
__global__ void __launch_bounds__(1024) k4b_fallback(const float* __restrict__ cls,
                                                     const float* __restrict__ cent){
    const int n = blockIdx.x;
    if (!g_flag[n]) return;
    const int tid = threadIdx.x;
    __shared__ unsigned int hist[NBINS];
    __shared__ unsigned int csum[256];
    __shared__ unsigned long long keys[CAND_MAX];
    __shared__ unsigned int lcnt, s_cut;
    for (int i = tid; i < NBINS; i += 1024) hist[i] = 0u;
    if (tid == 0) lcnt = 0u;
    g_top[n][tid] = 0ull;
    __syncthreads();
    const float* cls_n  = cls  + (size_t)n * M;
    const float* cent_n = cent + (size_t)n * HW;
    for (int e = tid; e < M; e += 1024){
        float p = sigmoid_exact(cls_n[e]);
        if (p > PRE_T){
            int c = e / HW; int hw = e - c * HW;
            float s = p * sigmoid_exact(cent_n[hw]);
            atomicAdd(&hist[__float_as_uint(s) >> BIN_SHIFT], 1u);
        }
    }
    __syncthreads();
    if (tid < 256){
        unsigned int s = 0;
        int base = tid * 8;
        #pragma unroll
        for (int i = 0; i < 8; ++i) s += hist[base + i];
        csum[tid] = s;
    }
    __syncthreads();
    if (tid == 0){
        unsigned int acc = 0; int cut = 0; int c = 255;
        for (; c >= 0; --c){ if (acc + csum[c] >= TOPK) break; acc += csum[c]; }
        if (c >= 0){
            int b = c*8 + 7;
            for (;; --b){ acc += hist[b]; if (acc >= TOPK || b == c*8) break; }
            cut = b;
        }
        while (acc > CAND_MAX && cut < NBINS){ acc -= hist[cut]; cut++; }
        s_cut = (unsigned int)cut;
    }
    __syncthreads();
    unsigned int cutb = s_cut;
    for (int e = tid; e < M; e += 1024){
        float p = sigmoid_exact(cls_n[e]);
        if (p > PRE_T){
            int c = e / HW; int hw = e - c * HW;
            float s = p * sigmoid_exact(cent_n[hw]);
            unsigned int bits = __float_as_uint(s);
            if ((bits >> BIN_SHIFT) >= cutb){
                unsigned int pos = atomicAdd(&lcnt, 1u);
                if (pos < CAND_MAX){
                    unsigned int idx = (unsigned int)(hw * NCLS + c);
                    keys[pos] = ((unsigned long long)bits << 32)
                              | (unsigned long long)(0xFFFFFFFFu - idx);
                }
            }
        }
    }
    __syncthreads();
    int C = (int)(lcnt < CAND_MAX ? lcnt : CAND_MAX);
    for (int i = tid; i < C; i += 1024){
        unsigned long long k = keys[i];
        int rank = 0;
        for (int j = 0; j < C; ++j) rank += (keys[j] > k) ? 1 : 0;
        if (rank < TOPK) g_top[n][rank] = k;
    }
}

// k5: decode boxes, greedy NMS with early stop at 100 keeps, write output
__global__ void __launch_bounds__(1024) k5_nms(const float* __restrict__ loc,
                                               const float* __restrict__ reg,
                                               const int*   __restrict__ imsz,
                                               float* __restrict__ out){
    int n = blockIdx.x;
    int t = threadIdx.x;
    __shared__ float ox1[TOPK], oy1[TOPK], ox2[TOPK], oy2[TOPK], oar[TOPK];
    __shared__ float bx[TOPK][4];
    __shared__ float sc[TOPK];
    __shared__ int   lab[TOPK];
    __shared__ unsigned char validf[TOPK];
    __shared__ unsigned char supp[TOPK];
    __shared__ int keeplist[OUTK];

    if (t < TOPK){
        unsigned long long k = g_top[n][t];
        unsigned int bits = (unsigned int)(k >> 32);
        float s = __uint_as_float(bits);
        supp[t] = 0;
        if (s > 0.0f){
            unsigned int idx = 0xFFFFFFFFu - (unsigned int)(k & 0xFFFFFFFFull);
            int hw = (int)(idx / NCLS);
            int c  = (int)(idx % NCLS);
            int l  = c + 1;
            float x  = loc[2*hw], y = loc[2*hw + 1];
            float r0 = reg[((size_t)n*4 + 0)*HW + hw];
            float r1 = reg[((size_t)n*4 + 1)*HW + hw];
            float r2 = reg[((size_t)n*4 + 2)*HW + hw];
            float r3 = reg[((size_t)n*4 + 3)*HW + hw];
            float ihh = (float)imsz[2*n + 0];
            float iww = (float)imsz[2*n + 1];
            float x1 = fminf(fmaxf(x - r0, 0.0f), iww - 1.0f);
            float y1 = fminf(fmaxf(y - r1, 0.0f), ihh - 1.0f);
            float x2 = fminf(fmaxf(x + r2, 0.0f), iww - 1.0f);
            float y2 = fminf(fmaxf(y + r3, 0.0f), ihh - 1.0f);
            bx[t][0] = x1; bx[t][1] = y1; bx[t][2] = x2; bx[t][3] = y2;
            float off = (float)l * 100000.0f;   // fp32, as reference (quantizes!)
            float a1 = x1 + off, b1 = y1 + off, a2 = x2 + off, b2 = y2 + off;
            ox1[t] = a1; oy1[t] = b1; ox2[t] = a2; oy2[t] = b2;
            oar[t] = (a2 - a1 + 1.0f) * (b2 - b1 + 1.0f);
            sc[t] = s; lab[t] = l; validf[t] = 1;
        } else {
            validf[t] = 0; sc[t] = 0.0f; lab[t] = 0;
            bx[t][0] = bx[t][1] = bx[t][2] = bx[t][3] = 0.0f;
            ox1[t] = oy1[t] = 0.0f; ox2[t] = oy2[t] = -1.0f; oar[t] = 1.0f;
        }
    }
    __syncthreads();

    int cnt = 0;
    for (int i = 0; i < TOPK; ++i){
        bool keep_i = validf[i] && !supp[i];   // uniform LDS broadcast
        if (keep_i){
            if (t == 0) keeplist[cnt] = i;
            if (t < TOPK && t != i){
                float ix1 = fmaxf(ox1[i], ox1[t]);
                float iy1 = fmaxf(oy1[i], oy1[t]);
                float ix2 = fminf(ox2[i], ox2[t]);
                float iy2 = fminf(oy2[i], oy2[t]);
                float iw_ = fmaxf(ix2 - ix1 + 1.0f, 0.0f);
                float ih_ = fmaxf(iy2 - iy1 + 1.0f, 0.0f);
                float inter = iw_ * ih_;
                float iou = inter / (oar[i] + oar[t] - inter);
                if (iou > NMS_T) supp[t] = 1;
            }
            cnt++;
            __syncthreads();
            if (cnt == OUTK) break;    // keeps beyond 100 can't reach output
        }
    }
    __syncthreads();

    if (t < OUTK){
        float r0=0.f,r1=0.f,r2=0.f,r3=0.f,r4=0.f,r5=0.f;
        if (t < cnt){
            int i = keeplist[t];
            r0 = bx[i][0]; r1 = bx[i][1]; r2 = bx[i][2]; r3 = bx[i][3];
            r4 = sqrtf(sc[i]); r5 = (float)lab[i];
        }
        float* o = out + ((size_t)n*OUTK + t)*6;
        o[0]=r0; o[1]=r1; o[2]=r2; o[3]=r3; o[4]=r4; o[5]=r5;
    }
}

extern "C" void kernel_launch(void* const* d_in, const int* in_sizes, int n_in,
                              void* d_out, int out_size, void* d_ws, size_t ws_size,
                              hipStream_t stream){
    const float* loc  = (const float*)d_in[0];
    const float* cls  = (const float*)d_in[1];
    const float* reg  = (const float*)d_in[2];
    const float* cent = (const float*)d_in[3];
    const int*   imsz = (const int*)d_in[4];
    float* out = (float*)d_out;

    hipLaunchKernelGGL(k0_init,      dim3(625),                  dim3(512),  0, stream, cent);
    hipLaunchKernelGGL(k1_spill,     dim3((M+4095)/4096, NIMG),  dim3(1024), 0, stream, cls);
    hipLaunchKernelGGL(k4_select,    dim3(NIMG),                 dim3(1024), 0, stream, cls, cent);
    hipLaunchKernelGGL(k4b_fallback, dim3(NIMG),                 dim3(1024), 0, stream, cls, cent);
    hipLaunchKernelGGL(k5_nms,       dim3(NIMG),                 dim3(1024), 0, stream,
                       loc, reg, imsz, out);
}

// Round 7
// 319.369 us; speedup vs baseline: 3.1412x; 1.0540x over previous
//
#include <hip/hip_runtime.h>
#include <math.h>

#define NIMG 8
#define NCLS 80
#define HW 40000
#define M (NCLS*HW)          // 3,200,000 per image
#define NBINS 2048
#define NSUB 4096
#define BIN_SHIFT 20         // level-1: top 12 bits of positive float
#define CAND2 2304           // collect cap after 2-level cut (~1000 + ties)
#define CAND_MAX 4096        // fallback path cap
#define SPILL_CAP 65536
#define BCAP 1024
#define TOPK 1000
#define OUTK 100
#define PRE_T 0.05f
#define NMS_T 0.6f
#define FLOOR_S 0.25f        // fast-path floor: verified per-call via c025>=TOPK
#define FLOOR_SAFE 0.2494f

// device-global scratch; counters re-zeroed every call, rest guarded by counts
__device__ unsigned int       g_scnt[NIMG][32];    // padded: 128B per image
__device__ unsigned int       g_ovf[NIMG];
__device__ int                g_flag[NIMG];
__device__ float              g_xthr[NIMG * HW];   // 1.25 MB, L2-resident
__device__ unsigned int       g_spill[NIMG][SPILL_CAP];
__device__ unsigned long long g_key[NIMG][SPILL_CAP];
__device__ unsigned long long g_top[NIMG][1024];

__device__ __forceinline__ float sigmoid_exact(float x){
    return 1.0f / (1.0f + expf(-x));   // bit-matches ref (R1-R6: absmax 0)
}

// k0: zero counters; xthr[hw] = logit(FLOOR_SAFE / sigmoid(ct)), +inf if >=1.
__global__ void k0_init(const float* __restrict__ cent){
    int t = blockIdx.x * blockDim.x + threadIdx.x;
    if (t < NIMG * 32) ((unsigned int*)g_scnt)[t] = 0u;
    if (t < NIMG) g_ovf[t] = 0u;
    if (t < NIMG * HW){
        float pct = sigmoid_exact(cent[t]);
        float a = FLOOR_SAFE / pct;
        float xt;
        if (a >= 1.0f) xt = 3.0e38f;
        else {
            float am = fminf(a, 0.98f);
            xt = logf(am / (1.0f - am));
        }
        g_xthr[t] = xt;
    }
}

// k1: the ONLY full stream over cls. Raw-logit compare vs per-pixel threshold;
// LDS compaction, one global atomic per block (R6: this killed the 700us storm).
__global__ void __launch_bounds__(1024) k1_spill(const float* __restrict__ cls){
    const int n   = blockIdx.y;
    const int tid = threadIdx.x;
    const int e0  = blockIdx.x * 4096 + tid * 4;
    __shared__ unsigned int sidx[BCAP];
    __shared__ unsigned int lcnt, lbase;
    if (tid == 0) lcnt = 0u;
    __syncthreads();
    if (e0 < M){
        const int c  = e0 / HW;
        const int hw = e0 - c * HW;
        float4 x  = *(const float4*)(cls + (size_t)n * M + e0);
        float4 th = *(const float4*)(g_xthr + n * HW + hw);
        unsigned int ib = (unsigned int)(hw * NCLS + c);
        if (x.x >= th.x){ unsigned int p = atomicAdd(&lcnt, 1u); if (p < BCAP) sidx[p] = ib; }
        if (x.y >= th.y){ unsigned int p = atomicAdd(&lcnt, 1u); if (p < BCAP) sidx[p] = ib + NCLS; }
        if (x.z >= th.z){ unsigned int p = atomicAdd(&lcnt, 1u); if (p < BCAP) sidx[p] = ib + 2*NCLS; }
        if (x.w >= th.w){ unsigned int p = atomicAdd(&lcnt, 1u); if (p < BCAP) sidx[p] = ib + 3*NCLS; }
    }
    __syncthreads();
    unsigned int raw = lcnt;
    unsigned int cnt = raw < BCAP ? raw : BCAP;
    if (tid == 0){
        lbase = cnt ? atomicAdd(&g_scnt[n][0], cnt) : 0u;
        if (raw > BCAP) g_ovf[n] = 1u;
    }
    __syncthreads();
    unsigned int base = lbase;
    for (unsigned int i = tid; i < cnt; i += 1024){
        unsigned int pos = base + i;
        if (pos < SPILL_CAP) g_spill[n][pos] = sidx[i];
    }
}

// k4: exact re-score spills; TWO-LEVEL cut (bits 31:20, then 19:8 within the
// boundary bin) so C ~ 1000+ties instead of ~hist-bin-width (R6: only ~17
// level-1 bins cover [0.25,1) -> C was 1600-4000 -> O(C^2) was the 100us).
__global__ void __launch_bounds__(1024) k4_select(const float* __restrict__ cls,
                                                  const float* __restrict__ cent){
    const int n = blockIdx.x;
    const int tid = threadIdx.x;
    const int lane = tid & 63;
    __shared__ unsigned int hist[NBINS];
    __shared__ unsigned int subh[NSUB];
    __shared__ unsigned int cs1[256], cs2[256];
    __shared__ unsigned long long keys[CAND2];
    __shared__ unsigned int lcnt, c025, s_cut, s_sub, s_flag;
    for (int i = tid; i < NBINS; i += 1024) hist[i] = 0u;
    for (int i = tid; i < NSUB;  i += 1024) subh[i] = 0u;
    if (tid == 0){ lcnt = 0u; c025 = 0u; }
    g_top[n][tid] = 0ull;
    __syncthreads();
    unsigned int scnt_raw = g_scnt[n][0];
    unsigned int S = scnt_raw < SPILL_CAP ? scnt_raw : SPILL_CAP;
    const float* cls_n  = cls  + (size_t)n * M;
    const float* cent_n = cent + (size_t)n * HW;
    // pass 1: gather + exact score + level-1 hist + keys to global
    for (unsigned int i = tid; i < S; i += 1024){
        unsigned int idx = g_spill[n][i];
        unsigned int hw = idx / NCLS;
        unsigned int c  = idx - hw * NCLS;
        float x  = cls_n[(size_t)c * HW + hw];
        float ct = cent_n[hw];
        float p = sigmoid_exact(x);
        unsigned long long key = 0ull;
        bool f25 = false;
        if (p > PRE_T){
            float s = p * sigmoid_exact(ct);
            unsigned int bits = __float_as_uint(s);
            atomicAdd(&hist[bits >> BIN_SHIFT], 1u);
            f25 = (s >= FLOOR_S);
            key = ((unsigned long long)bits << 32)
                | (unsigned long long)(0xFFFFFFFFu - idx);
        }
        unsigned long long mb = __ballot(f25);       // 1 atomic/wave not /lane
        if (lane == 0 && mb) atomicAdd(&c025, (unsigned int)__popcll(mb));
        g_key[n][i] = key;
    }
    __syncthreads();
    if (tid < 256){
        unsigned int s = 0;
        int base = tid * 8;
        #pragma unroll
        for (int i = 0; i < 8; ++i) s += hist[base + i];
        cs1[tid] = s;
    }
    __syncthreads();
    if (tid == 0){
        unsigned int acc = 0; int cut = 0; unsigned int A = 0;
        int c = 255;
        for (; c >= 0; --c){ if (acc + cs1[c] >= TOPK) break; acc += cs1[c]; }
        if (c >= 0){
            int b = c*8 + 7;
            for (;; --b){
                if (acc + hist[b] >= TOPK || b == c*8){ cut = b; A = acc; break; }
                acc += hist[b];
            }
        } else { cut = 0; A = acc - hist[0]; }   // total < TOPK
        s_cut = (unsigned int)cut;
        subh[NSUB-1] += 0u;                      // keep subh live
        cs1[0] = A;                              // stash A for后 phases
    }
    __syncthreads();
    unsigned int cut = s_cut;
    unsigned int A = cs1[0];
    // pass 2: sub-histogram (bits 19:8) of keys inside the boundary bin
    for (unsigned int i = tid; i < S; i += 1024){
        unsigned long long k = g_key[n][i];
        if (k && (unsigned int)(k >> 52) == cut)
            atomicAdd(&subh[(unsigned int)(k >> 40) & 0xFFFu], 1u);
    }
    __syncthreads();
    if (tid < 256){
        unsigned int s = 0;
        int base = tid * 16;
        #pragma unroll
        for (int i = 0; i < 16; ++i) s += subh[base + i];
        cs2[tid] = s;
    }
    __syncthreads();
    if (tid == 0){
        int needed = TOPK - (int)A;              // >= 1 always
        unsigned int acc2 = 0; int sub = 0; unsigned int accAt;
        int c2 = 255;
        for (; c2 >= 0; --c2){ if ((int)(acc2 + cs2[c2]) >= needed) break; acc2 += cs2[c2]; }
        if (c2 >= 0){
            int b = c2*16 + 15;
            for (;; --b){
                acc2 += subh[b];
                if ((int)acc2 >= needed || b == c2*16) break;
            }
            sub = b; accAt = acc2;
        } else { sub = 0; accAt = acc2; }
        unsigned int C = A + accAt;
        unsigned int fl = (scnt_raw > SPILL_CAP) || g_ovf[n] ||
                          (c025 < TOPK) || (C > CAND2) ? 1u : 0u;
        s_sub = (unsigned int)sub; s_flag = fl; g_flag[n] = (int)fl;
    }
    __syncthreads();
    if (s_flag) return;
    unsigned int sub = s_sub;
    // pass 3: collect (ballot-compacted append)
    for (unsigned int i = tid; i < S; i += 1024){
        unsigned long long k = g_key[n][i];
        unsigned int bin = (unsigned int)(k >> 52);
        bool pass = k && (bin > cut ||
                    (bin == cut && ((unsigned int)(k >> 40) & 0xFFFu) >= sub));
        unsigned long long mb = __ballot(pass);
        unsigned int wcnt = (unsigned int)__popcll(mb);
        unsigned int base = 0;
        if (lane == 0 && wcnt) base = atomicAdd(&lcnt, wcnt);
        base = (unsigned int)__builtin_amdgcn_readfirstlane((int)base);
        if (pass){
            unsigned int p = base + (unsigned int)__popcll(mb & ((1ull << lane) - 1ull));
            if (p < CAND2) keys[p] = k;
        }
    }
    __syncthreads();
    int C = (int)(lcnt < CAND2 ? lcnt : CAND2);
    for (int i = tid; i < C; i += 1024){
        unsigned long long k = keys[i];
        int rank = 0;
        for (int j = 0; j < C; ++j) rank += (keys[j] > k) ? 1 : 0;
        if (rank < TOPK) g_top[n][rank] = k;
    }
}

// k4b: guaranteed-correct full exact rescan; normally early-exits (flag==0).
__global__ void __launch_bounds__(1024) k4b_fallback(const float* __restrict__ cls,
                                                     const float* __restrict__ cent){
    const int n = blockIdx.x;
    if (!g_flag[n]) return;
    const int tid = threadIdx.x;
    __shared__ unsigned int hist[NBINS];
    __shared__ unsigned int csum[256];
    __shared__ unsigned long long keys[CAND_MAX];
    __shared__ unsigned int lcnt, s_cut;
    for (int i = tid; i < NBINS; i += 1024) hist[i] = 0u;
    if (tid == 0) lcnt = 0u;
    g_top[n][tid] = 0ull;
    __syncthreads();
    const float* cls_n  = cls  + (size_t)n * M;
    const float* cent_n = cent + (size_t)n * HW;
    for (int e = tid; e < M; e += 1024){
        float p = sigmoid_exact(cls_n[e]);
        if (p > PRE_T){
            int c = e / HW; int hw = e - c * HW;
            float s = p * sigmoid_exact(cent_n[hw]);
            atomicAdd(&hist[__float_as_uint(s) >> BIN_SHIFT], 1u);
        }
    }
    __syncthreads();
    if (tid < 256){
        unsigned int s = 0;
        int base = tid * 8;
        #pragma unroll
        for (int i = 0; i < 8; ++i) s += hist[base + i];
        csum[tid] = s;
    }
    __syncthreads();
    if (tid == 0){
        unsigned int acc = 0; int cut = 0; int c = 255;
        for (; c >= 0; --c){ if (acc + csum[c] >= TOPK) break; acc += csum[c]; }
        if (c >= 0){
            int b = c*8 + 7;
            for (;; --b){ acc += hist[b]; if (acc >= TOPK || b == c*8) break; }
            cut = b;
        }
        while (acc > CAND_MAX && cut < NBINS){ acc -= hist[cut]; cut++; }
        s_cut = (unsigned int)cut;
    }
    __syncthreads();
    unsigned int cutb = s_cut;
    for (int e = tid; e < M; e += 1024){
        float p = sigmoid_exact(cls_n[e]);
        if (p > PRE_T){
            int c = e / HW; int hw = e - c * HW;
            float s = p * sigmoid_exact(cent_n[hw]);
            unsigned int bits = __float_as_uint(s);
            if ((bits >> BIN_SHIFT) >= cutb){
                unsigned int pos = atomicAdd(&lcnt, 1u);
                if (pos < CAND_MAX){
                    unsigned int idx = (unsigned int)(hw * NCLS + c);
                    keys[pos] = ((unsigned long long)bits << 32)
                              | (unsigned long long)(0xFFFFFFFFu - idx);
                }
            }
        }
    }
    __syncthreads();
    int C = (int)(lcnt < CAND_MAX ? lcnt : CAND_MAX);
    for (int i = tid; i < C; i += 1024){
        unsigned long long k = keys[i];
        int rank = 0;
        for (int j = 0; j < C; ++j) rank += (keys[j] > k) ? 1 : 0;
        if (rank < TOPK) g_top[n][rank] = k;
    }
}

// k5: 256 threads, 4 register-resident boxes/thread. Keep-iterations: 4 IoUs
// + 4-wave barrier (was 16-wave). Skip-iterations barrier-free.
__global__ void __launch_bounds__(256) k5_nms(const float* __restrict__ loc,
                                              const float* __restrict__ reg,
                                              const int*   __restrict__ imsz,
                                              float* __restrict__ out){
    const int n = blockIdx.x;
    const int t = threadIdx.x;
    __shared__ float ox1[TOPK], oy1[TOPK], ox2[TOPK], oy2[TOPK], oar[TOPK];
    __shared__ float bxs[TOPK][4];
    __shared__ float sc[TOPK];
    __shared__ int   lab[TOPK];
    __shared__ unsigned char validf[TOPK];
    __shared__ unsigned char supp[TOPK];
    __shared__ int keeplist[OUTK];
    float rx1[4], ry1[4], rx2[4], ry2[4], rar[4];

    float ihh = (float)imsz[2*n + 0];
    float iww = (float)imsz[2*n + 1];
    #pragma unroll
    for (int q = 0; q < 4; ++q){
        int i = t + 256*q;
        if (i >= TOPK){ rx1[q]=0.f; ry1[q]=0.f; rx2[q]=-1.f; ry2[q]=-1.f; rar[q]=1.f; continue; }
        unsigned long long k = g_top[n][i];
        unsigned int bits = (unsigned int)(k >> 32);
        float s = __uint_as_float(bits);
        supp[i] = 0;
        if (s > 0.0f){
            unsigned int idx = 0xFFFFFFFFu - (unsigned int)(k & 0xFFFFFFFFull);
            int hw = (int)(idx / NCLS);
            int c  = (int)(idx % NCLS);
            int l  = c + 1;
            float x  = loc[2*hw], y = loc[2*hw + 1];
            float r0 = reg[((size_t)n*4 + 0)*HW + hw];
            float r1 = reg[((size_t)n*4 + 1)*HW + hw];
            float r2 = reg[((size_t)n*4 + 2)*HW + hw];
            float r3 = reg[((size_t)n*4 + 3)*HW + hw];
            float x1 = fminf(fmaxf(x - r0, 0.0f), iww - 1.0f);
            float y1 = fminf(fmaxf(y - r1, 0.0f), ihh - 1.0f);
            float x2 = fminf(fmaxf(x + r2, 0.0f), iww - 1.0f);
            float y2 = fminf(fmaxf(y + r3, 0.0f), ihh - 1.0f);
            bxs[i][0] = x1; bxs[i][1] = y1; bxs[i][2] = x2; bxs[i][3] = y2;
            float off = (float)l * 100000.0f;   // fp32, as reference (quantizes!)
            float a1 = x1 + off, b1 = y1 + off, a2 = x2 + off, b2 = y2 + off;
            float ar = (a2 - a1 + 1.0f) * (b2 - b1 + 1.0f);
            ox1[i] = a1; oy1[i] = b1; ox2[i] = a2; oy2[i] = b2; oar[i] = ar;
            rx1[q] = a1; ry1[q] = b1; rx2[q] = a2; ry2[q] = b2; rar[q] = ar;
            sc[i] = s; lab[i] = l; validf[i] = 1;
        } else {
            validf[i] = 0; sc[i] = 0.0f; lab[i] = 0;
            bxs[i][0] = bxs[i][1] = bxs[i][2] = bxs[i][3] = 0.0f;
            ox1[i] = 0.f; oy1[i] = 0.f; ox2[i] = -1.f; oy2[i] = -1.f; oar[i] = 1.f;
            rx1[q] = 0.f; ry1[q] = 0.f; rx2[q] = -1.f; ry2[q] = -1.f; rar[q] = 1.f;
        }
    }
    __syncthreads();

    int cnt = 0;
    for (int i = 0; i < TOPK; ++i){
        bool keep_i = validf[i] && !supp[i];   // uniform LDS broadcast
        if (keep_i){
            if (t == 0) keeplist[cnt] = i;
            float bx1 = ox1[i], by1 = oy1[i], bx2 = ox2[i], by2 = oy2[i], ba = oar[i];
            #pragma unroll
            for (int q = 0; q < 4; ++q){
                int bi = t + 256*q;
                if (bi != i && bi < TOPK){
                    float ix1 = fmaxf(bx1, rx1[q]);
                    float iy1 = fmaxf(by1, ry1[q]);
                    float ix2 = fminf(bx2, rx2[q]);
                    float iy2 = fminf(by2, ry2[q]);
                    float iw_ = fmaxf(ix2 - ix1 + 1.0f, 0.0f);
                    float ih_ = fmaxf(iy2 - iy1 + 1.0f, 0.0f);
                    float inter = iw_ * ih_;
                    float iou = inter / (ba + rar[q] - inter);
                    if (iou > NMS_T) supp[bi] = 1;
                }
            }
            cnt++;
            __syncthreads();
            if (cnt == OUTK) break;    // keeps beyond 100 can't reach output
        }
    }
    __syncthreads();

    if (t < OUTK){
        float r0=0.f,r1=0.f,r2=0.f,r3=0.f,r4=0.f,r5=0.f;
        if (t < cnt){
            int i = keeplist[t];
            r0 = bxs[i][0]; r1 = bxs[i][1]; r2 = bxs[i][2]; r3 = bxs[i][3];
            r4 = sqrtf(sc[i]); r5 = (float)lab[i];
        }
        float* o = out + ((size_t)n*OUTK + t)*6;
        o[0]=r0; o[1]=r1; o[2]=r2; o[3]=r3; o[4]=r4; o[5]=r5;
    }
}

extern "C" void kernel_launch(void* const* d_in, const int* in_sizes, int n_in,
                              void* d_out, int out_size, void* d_ws, size_t ws_size,
                              hipStream_t stream){
    const float* loc  = (const float*)d_in[0];
    const float* cls  = (const float*)d_in[1];
    const float* reg  = (const float*)d_in[2];
    const float* cent = (const float*)d_in[3];
    const int*   imsz = (const int*)d_in[4];
    float* out = (float*)d_out;

    hipLaunchKernelGGL(k0_init,      dim3(625),                  dim3(512),  0, stream, cent);
    hipLaunchKernelGGL(k1_spill,     dim3((M+4095)/4096, NIMG),  dim3(1024), 0, stream, cls);
    hipLaunchKernelGGL(k4_select,    dim3(NIMG),                 dim3(1024), 0, stream, cls, cent);
    hipLaunchKernelGGL(k4b_fallback, dim3(NIMG),                 dim3(1024), 0, stream, cls, cent);
    hipLaunchKernelGGL(k5_nms,       dim3(NIMG),                 dim3(256),  0, stream,
                       loc, reg, imsz, out);
}

// Round 8
// 293.216 us; speedup vs baseline: 3.4214x; 1.0892x over previous
//
#include <hip/hip_runtime.h>
#include <math.h>

#define NIMG 8
#define NCLS 80
#define HW 40000
#define M (NCLS*HW)          // 3,200,000 per image
#define UBINS 4096           // uniform bins over s in [0,1): bin = (int)(s*4096)
#define CANDL 4096           // collect cap (fast path C ~ 1005)
#define SPILL_CAP 65536
#define BCAP 1024
#define TOPK 1000
#define OUTK 100
#define PRE_T 0.05f
#define NMS_T 0.6f
#define FLOOR_S 0.25f        // fast-path floor: verified per-call via c025>=TOPK
#define FLOOR_BITS 0x3E800000u
#define FLOOR_SAFE 0.2494f

// device-global scratch; counters re-zeroed every call, rest guarded by counts
__device__ unsigned int       g_scnt[NIMG][32];    // padded: 128B per image
__device__ unsigned int       g_ovf[NIMG];
__device__ float              g_xthr[NIMG * HW];   // 1.25 MB, L2-resident
__device__ float              g_sct[NIMG * HW];    // exact sigmoid(centerness)
__device__ unsigned long long g_key[NIMG][SPILL_CAP];

__device__ __forceinline__ float sigmoid_exact(float x){
    return 1.0f / (1.0f + expf(-x));   // bit-matches ref (R1-R7: absmax 0)
}

// k0: zero counters; exact sct table; xthr[hw] = logit(FLOOR_SAFE/sct), +inf if >=1.
// Spill rule x >= xthr is a strict superset of {exact score >= FLOOR_S}:
// 0.2494 vs 0.25 = 2.4e-3 rel margin; logit slope capped by the 0.98 clamp.
__global__ void k0_init(const float* __restrict__ cent){
    int t = blockIdx.x * blockDim.x + threadIdx.x;
    if (t < NIMG * 32) ((unsigned int*)g_scnt)[t] = 0u;
    if (t < NIMG) g_ovf[t] = 0u;
    if (t < NIMG * HW){
        float pct = sigmoid_exact(cent[t]);
        g_sct[t] = pct;
        float a = FLOOR_SAFE / pct;
        float xt;
        if (a >= 1.0f) xt = 3.0e38f;
        else {
            float am = fminf(a, 0.98f);
            xt = logf(am / (1.0f - am));
        }
        g_xthr[t] = xt;
    }
}

// k1: the ONLY full stream over cls. Raw-logit compare vs per-pixel threshold
// (hot path identical to R6/R7 — proven). Spilling lanes (~0.1%) compute the
// EXACT 64-bit ranking key right here (expf + sct-table load), distributing
// the expf/gather cost over 6256 blocks instead of 8 single-CU blocks (R7's
// 74us k4 gather phase).
__global__ void __launch_bounds__(1024) k1_spill(const float* __restrict__ cls){
    const int n   = blockIdx.y;
    const int tid = threadIdx.x;
    const int e0  = blockIdx.x * 4096 + tid * 4;
    __shared__ unsigned long long skey[BCAP];
    __shared__ unsigned int lcnt, lbase;
    if (tid == 0) lcnt = 0u;
    __syncthreads();
    if (e0 < M){
        const int c  = e0 / HW;
        const int hw = e0 - c * HW;
        float4 x  = *(const float4*)(cls + (size_t)n * M + e0);
        float4 th = *(const float4*)(g_xthr + n * HW + hw);
        #define SPILL1(J, XV) \
        if (XV >= (J==0?th.x:J==1?th.y:J==2?th.z:th.w)){ \
            float p_ = sigmoid_exact(XV); \
            if (p_ > PRE_T){ \
                float s_ = p_ * g_sct[n * HW + hw + J]; \
                unsigned long long key_ = ((unsigned long long)__float_as_uint(s_) << 32) \
                    | (unsigned long long)(0xFFFFFFFFu - (unsigned int)((hw + J) * NCLS + c)); \
                unsigned int pp_ = atomicAdd(&lcnt, 1u); \
                if (pp_ < BCAP) skey[pp_] = key_; \
            } \
        }
        SPILL1(0, x.x)
        SPILL1(1, x.y)
        SPILL1(2, x.z)
        SPILL1(3, x.w)
        #undef SPILL1
    }
    __syncthreads();
    unsigned int raw = lcnt;
    unsigned int cnt = raw < BCAP ? raw : BCAP;
    if (tid == 0){
        lbase = cnt ? atomicAdd(&g_scnt[n][0], cnt) : 0u;
        if (raw > BCAP) g_ovf[n] = 1u;
    }
    __syncthreads();
    unsigned int base = lbase;
    for (unsigned int i = tid; i < cnt; i += 1024){
        unsigned int pos = base + i;
        if (pos < SPILL_CAP) g_key[n][pos] = skey[i];
    }
}

struct SelPhase {
    unsigned int hist[UBINS];                 // 16 KB
    unsigned int cs[256];                     // 1 KB
    unsigned long long keysL[CANDL];          // 32 KB
};
struct NmsPhase {
    float ox1[TOPK], oy1[TOPK], ox2[TOPK], oy2[TOPK], oar[TOPK];
    float bxs[TOPK][4];
    float sc[TOPK];
    int   lab[TOPK];
    unsigned char validf[TOPK];
    unsigned char supp[TOPK];
    int   keeplist[OUTK];
};
union KU { SelPhase sel; NmsPhase nms; };     // ~50 KB (phases don't overlap)

// k2: per image — uniform-bin hist of exact key bits (coalesced reads), cut,
// collect, O(C^2) exact rank (C~1005), then NMS + output, all in one block.
// Fallback (flag) path: exact full rescan inside the same kernel.
__global__ void __launch_bounds__(1024) k2_select_nms(const float* __restrict__ cls,
                                                      const float* __restrict__ loc,
                                                      const float* __restrict__ reg,
                                                      const int*   __restrict__ imsz,
                                                      float* __restrict__ out){
    const int n = blockIdx.x;
    const int tid = threadIdx.x;
    const int lane = tid & 63;
    __shared__ KU u;
    __shared__ unsigned long long stop[TOPK];
    __shared__ unsigned int lcnt, c025, s_cut, s_flag;

    for (int i = tid; i < UBINS; i += 1024) u.sel.hist[i] = 0u;
    if (tid == 0){ lcnt = 0u; c025 = 0u; }
    if (tid < TOPK) stop[tid] = 0ull;
    __syncthreads();

    unsigned int scnt_raw = g_scnt[n][0];
    unsigned int S = scnt_raw < SPILL_CAP ? scnt_raw : SPILL_CAP;

    // hist pass: coalesced key reads; bin = (int)(s*4096) — exact *2^12 => monotone
    for (unsigned int i = tid; i < S; i += 1024){
        unsigned long long k = g_key[n][i];
        unsigned int bits = (unsigned int)(k >> 32);
        float s = __uint_as_float(bits);
        int bin = (int)(s * 4096.0f);
        atomicAdd(&u.sel.hist[bin], 1u);
        unsigned long long mb = __ballot(bits >= FLOOR_BITS);
        if (lane == 0 && mb) atomicAdd(&c025, (unsigned int)__popcll(mb));
    }
    __syncthreads();
    if (tid < 256){
        unsigned int s = 0;
        int base = tid * 16;
        #pragma unroll
        for (int i = 0; i < 16; ++i) s += u.sel.hist[base + i];
        u.sel.cs[tid] = s;
    }
    __syncthreads();
    if (tid == 0){
        unsigned int acc = 0; int cut = 0;
        int c = 255;
        for (; c >= 0; --c){ if (acc + u.sel.cs[c] >= TOPK) break; acc += u.sel.cs[c]; }
        unsigned int Cest = 0;
        if (c >= 0){
            int b = c*16 + 15;
            for (;; --b){
                if (acc + u.sel.hist[b] >= TOPK || b == c*16){ cut = b; break; }
                acc += u.sel.hist[b];
            }
            Cest = acc + u.sel.hist[cut];
        }
        unsigned int fl = (scnt_raw > SPILL_CAP) || g_ovf[n] || (c < 0) ||
                          (c025 < TOPK) || (Cest > CANDL) ? 1u : 0u;
        s_cut = (unsigned int)cut; s_flag = fl;
    }
    __syncthreads();

    if (s_flag){
        // ---- fallback: exact full rescan (correctness insurance; ~never taken)
        for (int i = tid; i < UBINS; i += 1024) u.sel.hist[i] = 0u;
        __syncthreads();
        const float* cls_n = cls + (size_t)n * M;
        const float* sct_n = g_sct + n * HW;
        for (int e = tid; e < M; e += 1024){
            float p = sigmoid_exact(cls_n[e]);
            if (p > PRE_T){
                int c = e / HW; int hw = e - c * HW;
                float s = p * sct_n[hw];
                atomicAdd(&u.sel.hist[(int)(s * 4096.0f)], 1u);
            }
        }
        __syncthreads();
        if (tid < 256){
            unsigned int s = 0;
            int base = tid * 16;
            #pragma unroll
            for (int i = 0; i < 16; ++i) s += u.sel.hist[base + i];
            u.sel.cs[tid] = s;
        }
        __syncthreads();
        if (tid == 0){
            unsigned int acc = 0; int cut = 0; int c = 255;
            for (; c >= 0; --c){ if (acc + u.sel.cs[c] >= TOPK) break; acc += u.sel.cs[c]; }
            if (c >= 0){
                int b = c*16 + 15;
                for (;; --b){ acc += u.sel.hist[b]; if (acc >= TOPK || b == c*16) break; }
                cut = b;
            }
            while (acc > CANDL && cut < UBINS){ acc -= u.sel.hist[cut]; cut++; }
            s_cut = (unsigned int)cut;
        }
        __syncthreads();
        unsigned int cutb = s_cut;
        for (int e = tid; e < M; e += 1024){
            float p = sigmoid_exact(cls_n[e]);
            if (p > PRE_T){
                int c = e / HW; int hw = e - c * HW;
                float s = p * sct_n[hw];
                if ((int)(s * 4096.0f) >= (int)cutb){
                    unsigned int pos = atomicAdd(&lcnt, 1u);
                    if (pos < CANDL){
                        unsigned int idx = (unsigned int)(hw * NCLS + c);
                        u.sel.keysL[pos] = ((unsigned long long)__float_as_uint(s) << 32)
                                         | (unsigned long long)(0xFFFFFFFFu - idx);
                    }
                }
            }
        }
    } else {
        // ---- fast path: collect keys with bin >= cut (ballot-compacted)
        unsigned int cutb = s_cut;
        for (unsigned int i = tid; i < S; i += 1024){
            unsigned long long k = g_key[n][i];
            float s = __uint_as_float((unsigned int)(k >> 32));
            bool pass = ((unsigned int)(int)(s * 4096.0f)) >= cutb;
            unsigned long long mb = __ballot(pass);
            unsigned int wcnt = (unsigned int)__popcll(mb);
            unsigned int base = 0;
            if (lane == 0 && wcnt) base = atomicAdd(&lcnt, wcnt);
            base = (unsigned int)__builtin_amdgcn_readfirstlane((int)base);
            if (pass){
                unsigned int p = base + (unsigned int)__popcll(mb & ((1ull << lane) - 1ull));
                if (p < CANDL) u.sel.keysL[p] = k;
            }
        }
    }
    __syncthreads();

    // exact rank-select top-1000 (unique composite keys -> unique ranks)
    int C = (int)(lcnt < CANDL ? lcnt : CANDL);
    for (int i = tid; i < C; i += 1024){
        unsigned long long k = u.sel.keysL[i];
        int rank = 0;
        for (int j = 0; j < C; ++j) rank += (u.sel.keysL[j] > k) ? 1 : 0;
        if (rank < TOPK) stop[rank] = k;
    }
    __syncthreads();

    // ---- NMS phase (u.nms aliases u.sel — all sel reads are done)
    float rx1 = 0.f, ry1 = 0.f, rx2 = -1.f, ry2 = -1.f, rar = 1.f;
    float ihh = (float)imsz[2*n + 0];
    float iww = (float)imsz[2*n + 1];
    unsigned long long kk = (tid < TOPK) ? stop[tid] : 0ull;
    __syncthreads();   // ensure stop reads complete before union reuse writes
    if (tid < TOPK){
        unsigned int bits = (unsigned int)(kk >> 32);
        float s = __uint_as_float(bits);
        u.nms.supp[tid] = 0;
        if (s > 0.0f){
            unsigned int idx = 0xFFFFFFFFu - (unsigned int)(kk & 0xFFFFFFFFull);
            int hw = (int)(idx / NCLS);
            int c  = (int)(idx % NCLS);
            int l  = c + 1;
            float x  = loc[2*hw], y = loc[2*hw + 1];
            float r0 = reg[((size_t)n*4 + 0)*HW + hw];
            float r1 = reg[((size_t)n*4 + 1)*HW + hw];
            float r2 = reg[((size_t)n*4 + 2)*HW + hw];
            float r3 = reg[((size_t)n*4 + 3)*HW + hw];
            float x1 = fminf(fmaxf(x - r0, 0.0f), iww - 1.0f);
            float y1 = fminf(fmaxf(y - r1, 0.0f), ihh - 1.0f);
            float x2 = fminf(fmaxf(x + r2, 0.0f), iww - 1.0f);
            float y2 = fminf(fmaxf(y + r3, 0.0f), ihh - 1.0f);
            u.nms.bxs[tid][0] = x1; u.nms.bxs[tid][1] = y1;
            u.nms.bxs[tid][2] = x2; u.nms.bxs[tid][3] = y2;
            float off = (float)l * 100000.0f;   // fp32, as reference (quantizes!)
            float a1 = x1 + off, b1 = y1 + off, a2 = x2 + off, b2 = y2 + off;
            float ar = (a2 - a1 + 1.0f) * (b2 - b1 + 1.0f);
            u.nms.ox1[tid] = a1; u.nms.oy1[tid] = b1;
            u.nms.ox2[tid] = a2; u.nms.oy2[tid] = b2; u.nms.oar[tid] = ar;
            rx1 = a1; ry1 = b1; rx2 = a2; ry2 = b2; rar = ar;
            u.nms.sc[tid] = s; u.nms.lab[tid] = l; u.nms.validf[tid] = 1;
        } else {
            u.nms.validf[tid] = 0; u.nms.sc[tid] = 0.0f; u.nms.lab[tid] = 0;
            u.nms.bxs[tid][0] = u.nms.bxs[tid][1] = 0.0f;
            u.nms.bxs[tid][2] = u.nms.bxs[tid][3] = 0.0f;
            u.nms.ox1[tid] = 0.f; u.nms.oy1[tid] = 0.f;
            u.nms.ox2[tid] = -1.f; u.nms.oy2[tid] = -1.f; u.nms.oar[tid] = 1.f;
        }
    }
    __syncthreads();

    int cnt = 0;
    for (int i = 0; i < TOPK; ++i){
        bool keep_i = u.nms.validf[i] && !u.nms.supp[i];   // uniform LDS broadcast
        if (keep_i){
            if (tid == 0) u.nms.keeplist[cnt] = i;
            if (tid < TOPK && tid != i){
                float ix1 = fmaxf(u.nms.ox1[i], rx1);
                float iy1 = fmaxf(u.nms.oy1[i], ry1);
                float ix2 = fminf(u.nms.ox2[i], rx2);
                float iy2 = fminf(u.nms.oy2[i], ry2);
                float iw_ = fmaxf(ix2 - ix1 + 1.0f, 0.0f);
                float ih_ = fmaxf(iy2 - iy1 + 1.0f, 0.0f);
                float inter = iw_ * ih_;
                float iou = inter / (u.nms.oar[i] + rar - inter);
                if (iou > NMS_T) u.nms.supp[tid] = 1;
            }
            cnt++;
            __syncthreads();
            if (cnt == OUTK) break;    // keeps beyond 100 can't reach output
        }
    }
    __syncthreads();

    if (tid < OUTK){
        float r0=0.f,r1=0.f,r2=0.f,r3=0.f,r4=0.f,r5=0.f;
        if (tid < cnt){
            int i = u.nms.keeplist[tid];
            r0 = u.nms.bxs[i][0]; r1 = u.nms.bxs[i][1];
            r2 = u.nms.bxs[i][2]; r3 = u.nms.bxs[i][3];
            r4 = sqrtf(u.nms.sc[i]); r5 = (float)u.nms.lab[i];
        }
        float* o = out + ((size_t)n*OUTK + tid)*6;
        o[0]=r0; o[1]=r1; o[2]=r2; o[3]=r3; o[4]=r4; o[5]=r5;
    }
}

extern "C" void kernel_launch(void* const* d_in, const int* in_sizes, int n_in,
                              void* d_out, int out_size, void* d_ws, size_t ws_size,
                              hipStream_t stream){
    const float* loc  = (const float*)d_in[0];
    const float* cls  = (const float*)d_in[1];
    const float* reg  = (const float*)d_in[2];
    const float* cent = (const float*)d_in[3];
    const int*   imsz = (const int*)d_in[4];
    float* out = (float*)d_out;

    hipLaunchKernelGGL(k0_init,       dim3(625),                 dim3(512),  0, stream, cent);
    hipLaunchKernelGGL(k1_spill,      dim3((M+4095)/4096, NIMG), dim3(1024), 0, stream, cls);
    hipLaunchKernelGGL(k2_select_nms, dim3(NIMG),                dim3(1024), 0, stream,
                       cls, loc, reg, imsz, out);
}